// Round 1
// baseline (8310.934 us; speedup 1.0000x reference)
//
#include <hip/hip_runtime.h>

// ---------------------------------------------------------------------------
// LSTM LM: logp = log_softmax(scan_LSTM(emb[seq] @ W_ih^T + b) @ W_out^T + b_out)
// T=2048, H=1024, E=1024, V=32000.  ALL inputs/outputs are float32 (reference
// dtype).  Internally: GEMMs run bf16 MFMA (inputs cast once), the sequential
// scan runs fp32 (where rounding error would compound over 2048 steps).
// ---------------------------------------------------------------------------

typedef __attribute__((ext_vector_type(8))) short short8;
typedef __attribute__((ext_vector_type(4))) float f32x4;
typedef __attribute__((ext_vector_type(4))) int i32x4;
typedef __attribute__((ext_vector_type(4))) unsigned short u16x4;

__device__ __forceinline__ float bf2f(unsigned short u) {
    unsigned int x = ((unsigned int)u) << 16;
    return __builtin_bit_cast(float, x);
}
__device__ __forceinline__ unsigned short f2bf(float f) {
    unsigned int x = __builtin_bit_cast(unsigned int, f);
    x += 0x7FFFu + ((x >> 16) & 1u);   // round-to-nearest-even
    return (unsigned short)(x >> 16);
}

// ---------------------------------------------------------------------------
// fp32 -> bf16 cast, 4 elems/thread (n4 = n/4, n % 4 == 0)
// ---------------------------------------------------------------------------
__global__ __launch_bounds__(256) void cast_f2b(
    const float* __restrict__ src, unsigned short* __restrict__ dst, int n4)
{
    int i = blockIdx.x * 256 + threadIdx.x;
    if (i < n4) {
        f32x4 v = ((const f32x4*)src)[i];
        u16x4 o;
        o.x = f2bf(v.x); o.y = f2bf(v.y); o.z = f2bf(v.z); o.w = f2bf(v.w);
        ((u16x4*)dst)[i] = o;
    }
}

// ---------------------------------------------------------------------------
// xbf[t][:] = bf16(emb[seq[t]][:])   (one block per t, 4 elems/thread, E=1024)
// ---------------------------------------------------------------------------
__global__ __launch_bounds__(256) void gather_cast(
    const int* __restrict__ seq, const float* __restrict__ emb,
    unsigned short* __restrict__ xbf)
{
    int t = blockIdx.x, i = threadIdx.x;
    const f32x4* src = (const f32x4*)(emb + (size_t)seq[t] * 1024);
    f32x4 v = src[i];
    u16x4 o;
    o.x = f2bf(v.x); o.y = f2bf(v.y); o.z = f2bf(v.z); o.w = f2bf(v.w);
    ((u16x4*)(xbf + (size_t)t * 1024))[i] = o;
}

__global__ void init_h(const float* __restrict__ h0, float* __restrict__ hbuf)
{
    int i = blockIdx.x * 256 + threadIdx.x;
    if (i < 1024) hbuf[i] = h0[i];
}

// ---------------------------------------------------------------------------
// GEMM: C[M,N](fp32) = A[M,K] @ B[N,K]^T (+ bias0[n] + bias1[n]).  A,B bf16.
// 64x64 tile, BK=32, 256 thr = 4 waves; wave w owns C rows [16w,16w+16).
// mfma_f32_16x16x32_bf16: A-frag lane: row=lane&15, k=(lane>>4)*8+j
//                         B-frag (B^T): same pattern on B rows (= C cols)
//                         C/D: col=lane&15, row=(lane>>4)*4+reg  [m89/m91]
// ---------------------------------------------------------------------------
__global__ __launch_bounds__(256) void gemm_bt(
    const unsigned short* __restrict__ A, const unsigned short* __restrict__ B,
    const float* __restrict__ bias0, const float* __restrict__ bias1,
    float* __restrict__ C, int K, int ldc)
{
    __shared__ __align__(16) unsigned short As[64 * 40];  // +8 pad (2-way max: free)
    __shared__ __align__(16) unsigned short Bs[64 * 40];

    const int tid = threadIdx.x;
    const int m0 = blockIdx.y << 6, n0 = blockIdx.x << 6;
    const int wave = tid >> 6, lane = tid & 63, q = lane >> 4, l = lane & 15;

    f32x4 acc[4];
#pragma unroll
    for (int j = 0; j < 4; j++) acc[j] = (f32x4){0.f, 0.f, 0.f, 0.f};

    const int arow = tid >> 2;          // 0..63
    const int ach  = (tid & 3) * 8;     // 8-bf16 chunk within BK=32

    for (int k0 = 0; k0 < K; k0 += 32) {
        __syncthreads();
        i32x4 av = *(const i32x4*)(A + (size_t)(m0 + arow) * K + k0 + ach);
        i32x4 bv = *(const i32x4*)(B + (size_t)(n0 + arow) * K + k0 + ach);
        *(i32x4*)(&As[arow * 40 + ach]) = av;
        *(i32x4*)(&Bs[arow * 40 + ach]) = bv;
        __syncthreads();
        short8 a = *(const short8*)(&As[(wave * 16 + l) * 40 + q * 8]);
#pragma unroll
        for (int j = 0; j < 4; j++) {
            short8 b = *(const short8*)(&Bs[(j * 16 + l) * 40 + q * 8]);
            acc[j] = __builtin_amdgcn_mfma_f32_16x16x32_bf16(a, b, acc[j], 0, 0, 0);
        }
    }

#pragma unroll
    for (int j = 0; j < 4; j++) {
        int col = n0 + j * 16 + l;
        float bias = 0.f;
        if (bias0) bias += bias0[col];
        if (bias1) bias += bias1[col];
        int row0 = m0 + wave * 16 + q * 4;
#pragma unroll
        for (int r = 0; r < 4; r++)
            C[(size_t)(row0 + r) * ldc + col] = acc[j][r] + bias;
    }
}

// ---------------------------------------------------------------------------
// Persistent LSTM scan. 128 WGs x 256 thr (all co-resident on 256 CUs).
// WG blk owns units j in [8*blk, 8*blk+8). Thread (u=tid>>5, s=tid&31) does
// 4-gate partial dots for unit u over h[32s..32s+32), W_hh slice in 128 VGPRs
// (rotation by s makes LDS reads bank-conflict-free).
//
// Cross-WG transport (h double-buffer + flags) is done ENTIRELY with
// agent-scope RELAXED atomics: on gfx950 these carry SC=device and are
// serviced at the coherence point (LLC), bypassing the non-coherent per-XCD
// L2s.  So NO cache-maintenance fence (buffer_wbl2/buffer_inv) is needed —
// release ordering is one explicit s_waitcnt vmcnt(0) before the flag store;
// acquire ordering is in-order issue after the poll-loop branch + barrier.
// Flags are padded to 128 B apart (one LLC line each) so 8192 spinning
// pollers don't serialize on two hot lines.
//
// Skew between WGs is <=1 step, so the h double-buffer is WAR-safe
// (a WG enters step t only after ALL WGs posted t, i.e. finished step t-1
// including their read of buffer (t-1)&1 = (t+1)&1).
// ---------------------------------------------------------------------------
#define NWG 128
#define FSTRIDE 32   // ints: 128 B per flag -> one cache line each
__global__ __launch_bounds__(256, 1) void lstm_scan(
    const float* __restrict__ Whh, const float* __restrict__ xg,
    const float* __restrict__ c0, float* __restrict__ hbuf,
    unsigned short* __restrict__ hs, int* __restrict__ flags,
    float* __restrict__ outHT, float* __restrict__ outCT, int T)
{
    __shared__ float lh[1024];
    const int tid = threadIdx.x, blk = blockIdx.x;
    const int u = tid >> 5, s = tid & 31;
    const int j = blk * 8 + u;

    // stationary weights: w[g][k] = W_hh[g*1024+j][32*s + ((k+s)&31)]
    float w[4][32];
#pragma unroll
    for (int g = 0; g < 4; g++) {
        const float* wr = Whh + (size_t)(g * 1024 + j) * 1024 + s * 32;
#pragma unroll
        for (int k = 0; k < 32; k++) w[g][k] = wr[(k + s) & 31];
    }

    const bool owner = (s == 0);
    float cst = owner ? c0[j] : 0.f;

    for (int t = 0; t < T; t++) {
        // xg loads are independent of h: issue BEFORE the poll so the HBM
        // latency overlaps the wait for the previous step's producers.
        float xgi = 0.f, xgf = 0.f, xgg = 0.f, xgo = 0.f;
        if (owner) {
            const float* xp = xg + (size_t)t * 4096 + j;
            xgi = xp[0]; xgf = xp[1024]; xgg = xp[2048]; xgo = xp[3072];
        }

        if (t > 0) {
            if (tid < 64) {
                const int* fa = flags + tid * FSTRIDE;
                const int* fb = flags + (tid + 64) * FSTRIDE;
                for (;;) {
                    int f1 = __hip_atomic_load(fa, __ATOMIC_RELAXED,
                                               __HIP_MEMORY_SCOPE_AGENT);
                    int f2 = __hip_atomic_load(fb, __ATOMIC_RELAXED,
                                               __HIP_MEMORY_SCOPE_AGENT);
                    if (__all(f1 >= t && f2 >= t)) break;
                }
            }
            __syncthreads();
            // no buffer_inv needed: h is read below with agent-scope atomic
            // loads that bypass L1/L2 and observe the coherence point.
        }

        // broadcast h: coalesced (lane-consecutive dwords), LLC-direct.
        {
            const float* hb = hbuf + (t & 1) * 1024;
#pragma unroll
            for (int k2 = 0; k2 < 4; k2++) {
                float v = __hip_atomic_load(hb + tid + 256 * k2, __ATOMIC_RELAXED,
                                            __HIP_MEMORY_SCOPE_AGENT);
                lh[tid + 256 * k2] = v;   // bank = tid&31 -> 2-way alias, free
            }
        }
        __syncthreads();

        float a0 = 0.f, a1 = 0.f, a2 = 0.f, a3 = 0.f;
        const int base = s * 32;
#pragma unroll
        for (int k = 0; k < 32; k++) {
            float hk = lh[base + ((k + s) & 31)];
            a0 += w[0][k] * hk; a1 += w[1][k] * hk;
            a2 += w[2][k] * hk; a3 += w[3][k] * hk;
        }
#pragma unroll
        for (int d = 16; d; d >>= 1) {
            a0 += __shfl_down(a0, d, 32); a1 += __shfl_down(a1, d, 32);
            a2 += __shfl_down(a2, d, 32); a3 += __shfl_down(a3, d, 32);
        }

        float hv = 0.f;
        if (owner) {
            float gi = xgi + a0, gf = xgf + a1, gg = xgg + a2, go = xgo + a3;
            float iv = 1.f / (1.f + __expf(-gi));
            float fv = 1.f / (1.f + __expf(-gf));
            float gv = tanhf(gg);
            float ov = 1.f / (1.f + __expf(-go));
            cst = fv * cst + iv * gv;
            hv = ov * tanhf(cst);
            __hip_atomic_store(&hbuf[((t + 1) & 1) * 1024 + j], hv,
                               __ATOMIC_RELAXED, __HIP_MEMORY_SCOPE_AGENT);
            if (t == T - 1) { outHT[j] = hv; outCT[j] = cst; }
        }
        // release: drain this wave's h stores to the coherence point.
        asm volatile("s_waitcnt vmcnt(0)" ::: "memory");
        __syncthreads();
        if (tid == 0)
            __hip_atomic_store(&flags[blk * FSTRIDE], t + 1, __ATOMIC_RELAXED,
                               __HIP_MEMORY_SCOPE_AGENT);
        // hs is only consumed by the next kernel: store AFTER the flag post,
        // off the critical path (kernel-end flush makes it visible).
        if (owner) hs[(size_t)t * 1024 + j] = f2bf(hv);
    }
}

// ---------------------------------------------------------------------------
// In-place row log_softmax, fp32, V=32000. Two passes; pass 2 re-reads the
// L2-hot row. One WG (256 thr) per row, f32x4 vectorized (V/4 = 8000).
// ---------------------------------------------------------------------------
__global__ __launch_bounds__(256) void logsoftmax_rows(float* __restrict__ out, int V)
{
    __shared__ float redm[4], reds[4];
    const int tid = threadIdx.x;
    float* base = out + (size_t)blockIdx.x * V;
    const int n4 = V >> 2;

    float m = -3.0e38f, ssum = 0.f;
    for (int i = tid; i < n4; i += 256) {
        f32x4 v = ((const f32x4*)base)[i];
#pragma unroll
        for (int jj = 0; jj < 4; jj++) {
            float x = v[jj];
            if (x > m) { ssum = ssum * __expf(m - x) + 1.f; m = x; }
            else       { ssum += __expf(x - m); }
        }
    }
#pragma unroll
    for (int d = 32; d; d >>= 1) {
        float om = __shfl_down(m, d, 64);
        float os = __shfl_down(ssum, d, 64);
        float M = fmaxf(m, om);
        ssum = ssum * __expf(m - M) + os * __expf(om - M);
        m = M;
    }
    if ((tid & 63) == 0) { redm[tid >> 6] = m; reds[tid >> 6] = ssum; }
    __syncthreads();
    float M = fmaxf(fmaxf(redm[0], redm[1]), fmaxf(redm[2], redm[3]));
    float S = reds[0] * __expf(redm[0] - M) + reds[1] * __expf(redm[1] - M) +
              reds[2] * __expf(redm[2] - M) + reds[3] * __expf(redm[3] - M);
    float lse = M + logf(S);
    for (int i = tid; i < n4; i += 256) {
        f32x4 v = ((const f32x4*)base)[i];
        v.x -= lse; v.y -= lse; v.z -= lse; v.w -= lse;
        ((f32x4*)base)[i] = v;
    }
}

// ---------------------------------------------------------------------------
extern "C" void kernel_launch(void* const* d_in, const int* in_sizes, int n_in,
                              void* d_out, int out_size, void* d_ws, size_t ws_size,
                              hipStream_t stream)
{
    const int*   seq   = (const int*)d_in[0];
    const float* h0    = (const float*)d_in[1];
    const float* c0    = (const float*)d_in[2];
    const float* emb   = (const float*)d_in[3];
    const float* W_ih  = (const float*)d_in[4];
    const float* W_hh  = (const float*)d_in[5];
    const float* b_ih  = (const float*)d_in[6];
    const float* b_hh  = (const float*)d_in[7];
    const float* W_out = (const float*)d_in[8];
    const float* b_out = (const float*)d_in[9];

    const int T = 2048, H = 1024, V = 32000, G4 = 4096;

    // workspace layout (all regions fully written before read; flags memset)
    char* ws = (char*)d_ws;
    float*          xg     = (float*)ws;                           // 33,554,432 B
    unsigned short* Woutb  = (unsigned short*)(ws + 33554432);     // 65,536,000 B
    unsigned short* Wihb   = (unsigned short*)(ws + 99090432);     //  8,388,608 B
    unsigned short* xbf    = (unsigned short*)(ws + 107479040);    //  4,194,304 B
    unsigned short* hs     = (unsigned short*)(ws + 111673344);    //  4,194,304 B
    float*          hbuf   = (float*)(ws + 115867648);             //      8,192 B
    int*            flags  = (int*)(ws + 115875840);               //     16,384 B (128 x 128B)

    float* outp  = (float*)d_out;
    float* outHT = outp + (size_t)T * V;
    float* outCT = outHT + H;

    hipMemsetAsync(flags, 0, NWG * FSTRIDE * sizeof(int), stream);
    init_h<<<4, 256, 0, stream>>>(h0, hbuf);
    cast_f2b<<<(G4 * 1024 / 4 + 255) / 256, 256, 0, stream>>>(W_ih, Wihb, G4 * 1024 / 4);
    cast_f2b<<<(V * 1024 / 4 + 255) / 256, 256, 0, stream>>>(W_out, Woutb, V * 1024 / 4);
    gather_cast<<<T, 256, 0, stream>>>(seq, emb, xbf);

    // xg[T,4H] = xbf @ Wihb^T + (b_ih + b_hh), fp32
    gemm_bt<<<dim3(G4 / 64, T / 64), 256, 0, stream>>>(
        xbf, Wihb, b_ih, b_hh, xg, 1024, G4);

    // sequential scan -> hs[T,H] bf16, hT/cT fp32
    lstm_scan<<<NWG, 256, 0, stream>>>(W_hh, xg, c0, hbuf, hs, flags, outHT, outCT, T);

    // scores[T,V] = hs @ Woutb^T + b_out, fp32 directly into d_out
    gemm_bt<<<dim3(V / 64, T / 64), 256, 0, stream>>>(
        hs, Woutb, b_out, nullptr, outp, 1024, V);

    // in-place log_softmax per row
    logsoftmax_rows<<<T, 256, 0, stream>>>(outp, V);
}

// Round 2
// 6827.222 us; speedup vs baseline: 1.2173x; 1.2173x over previous
//
#include <hip/hip_runtime.h>

// ---------------------------------------------------------------------------
// LSTM LM: logp = log_softmax(scan_LSTM(emb[seq] @ W_ih^T + b) @ W_out^T + b_out)
// T=2048, H=1024, E=1024, V=32000.  ALL inputs/outputs are float32 (reference
// dtype).  Internally: GEMMs run bf16 MFMA (inputs cast once), the sequential
// scan runs fp32 (where rounding error would compound over 2048 steps).
// ---------------------------------------------------------------------------

typedef __attribute__((ext_vector_type(8))) short short8;
typedef __attribute__((ext_vector_type(4))) float f32x4;
typedef __attribute__((ext_vector_type(4))) int i32x4;
typedef __attribute__((ext_vector_type(4))) unsigned short u16x4;

__device__ __forceinline__ float bf2f(unsigned short u) {
    unsigned int x = ((unsigned int)u) << 16;
    return __builtin_bit_cast(float, x);
}
__device__ __forceinline__ unsigned short f2bf(float f) {
    unsigned int x = __builtin_bit_cast(unsigned int, f);
    x += 0x7FFFu + ((x >> 16) & 1u);   // round-to-nearest-even
    return (unsigned short)(x >> 16);
}

// ---------------------------------------------------------------------------
// fp32 -> bf16 cast, 4 elems/thread (n4 = n/4, n % 4 == 0)
// ---------------------------------------------------------------------------
__global__ __launch_bounds__(256) void cast_f2b(
    const float* __restrict__ src, unsigned short* __restrict__ dst, int n4)
{
    int i = blockIdx.x * 256 + threadIdx.x;
    if (i < n4) {
        f32x4 v = ((const f32x4*)src)[i];
        u16x4 o;
        o.x = f2bf(v.x); o.y = f2bf(v.y); o.z = f2bf(v.z); o.w = f2bf(v.w);
        ((u16x4*)dst)[i] = o;
    }
}

// ---------------------------------------------------------------------------
// xbf[t][:] = bf16(emb[seq[t]][:])   (one block per t, 4 elems/thread, E=1024)
// ---------------------------------------------------------------------------
__global__ __launch_bounds__(256) void gather_cast(
    const int* __restrict__ seq, const float* __restrict__ emb,
    unsigned short* __restrict__ xbf)
{
    int t = blockIdx.x, i = threadIdx.x;
    const f32x4* src = (const f32x4*)(emb + (size_t)seq[t] * 1024);
    f32x4 v = src[i];
    u16x4 o;
    o.x = f2bf(v.x); o.y = f2bf(v.y); o.z = f2bf(v.z); o.w = f2bf(v.w);
    ((u16x4*)(xbf + (size_t)t * 1024))[i] = o;
}

// ---------------------------------------------------------------------------
// hpair[2][1024]: 64-bit (tag<<32 | f32-bits-of-h) transport slots.
// parity-0 prefilled with (tag=0, h0); parity-1 with invalid tag.
// ---------------------------------------------------------------------------
__global__ void init_h(const float* __restrict__ h0,
                       unsigned long long* __restrict__ hpair)
{
    int i = blockIdx.x * 256 + threadIdx.x;
    if (i < 1024) {
        hpair[i] = (unsigned long long)__builtin_bit_cast(unsigned int, h0[i]);
        hpair[1024 + i] = 0xFFFFFFFF00000000ull;
    }
}

// ---------------------------------------------------------------------------
// GEMM: C[M,N](fp32) = A[M,K] @ B[N,K]^T (+ bias0[n] + bias1[n]).  A,B bf16.
// 64x64 tile, BK=32, 256 thr = 4 waves; wave w owns C rows [16w,16w+16).
// mfma_f32_16x16x32_bf16: A-frag lane: row=lane&15, k=(lane>>4)*8+j
//                         B-frag (B^T): same pattern on B rows (= C cols)
//                         C/D: col=lane&15, row=(lane>>4)*4+reg  [m89/m91]
// ---------------------------------------------------------------------------
__global__ __launch_bounds__(256) void gemm_bt(
    const unsigned short* __restrict__ A, const unsigned short* __restrict__ B,
    const float* __restrict__ bias0, const float* __restrict__ bias1,
    float* __restrict__ C, int K, int ldc)
{
    __shared__ __align__(16) unsigned short As[64 * 40];  // +8 pad (2-way max: free)
    __shared__ __align__(16) unsigned short Bs[64 * 40];

    const int tid = threadIdx.x;
    const int m0 = blockIdx.y << 6, n0 = blockIdx.x << 6;
    const int wave = tid >> 6, lane = tid & 63, q = lane >> 4, l = lane & 15;

    f32x4 acc[4];
#pragma unroll
    for (int j = 0; j < 4; j++) acc[j] = (f32x4){0.f, 0.f, 0.f, 0.f};

    const int arow = tid >> 2;          // 0..63
    const int ach  = (tid & 3) * 8;     // 8-bf16 chunk within BK=32

    for (int k0 = 0; k0 < K; k0 += 32) {
        __syncthreads();
        i32x4 av = *(const i32x4*)(A + (size_t)(m0 + arow) * K + k0 + ach);
        i32x4 bv = *(const i32x4*)(B + (size_t)(n0 + arow) * K + k0 + ach);
        *(i32x4*)(&As[arow * 40 + ach]) = av;
        *(i32x4*)(&Bs[arow * 40 + ach]) = bv;
        __syncthreads();
        short8 a = *(const short8*)(&As[(wave * 16 + l) * 40 + q * 8]);
#pragma unroll
        for (int j = 0; j < 4; j++) {
            short8 b = *(const short8*)(&Bs[(j * 16 + l) * 40 + q * 8]);
            acc[j] = __builtin_amdgcn_mfma_f32_16x16x32_bf16(a, b, acc[j], 0, 0, 0);
        }
    }

#pragma unroll
    for (int j = 0; j < 4; j++) {
        int col = n0 + j * 16 + l;
        float bias = 0.f;
        if (bias0) bias += bias0[col];
        if (bias1) bias += bias1[col];
        int row0 = m0 + wave * 16 + q * 4;
#pragma unroll
        for (int r = 0; r < 4; r++)
            C[(size_t)(row0 + r) * ldc + col] = acc[j][r] + bias;
    }
}

// ---------------------------------------------------------------------------
// Persistent LSTM scan. 128 WGs x 256 thr (all co-resident on 256 CUs).
// WG blk owns units j in [8*blk, 8*blk+8). Thread (u=tid>>5, s=tid&31) does
// 4-gate partial dots for unit u over h[32s..32s+32), W_hh slice in 128 VGPRs
// (rotation by s makes LDS reads bank-conflict-free).
//
// Transport: FUSED (tag, h) 64-bit slots, one per unit, double-buffered by
// step parity.  Producer: ONE relaxed agent-scope 8B atomic store — single-
// copy atomic, so the tag can never be seen without its h.  No vmcnt drain,
// no separate flag, no release fence.  Consumer: polls its 4 slots; a tag
// match IS the data (no second load).  Exact-match (== t) polling is safe:
// a tag t+2 overwrite of a parity slot requires every WG to have posted t+1,
// which (data dependency: the t+1 store's value is computed from the tag-t
// reads) requires every WG to have already consumed tag t.  Skew <= 1 is
// enforced by the all-to-all data dependency itself.
//
// LDS h-staging is double-buffered by parity -> ONE barrier per step.
// Cross-step LDS WAR (step t+2 poll-writes lh[t&1] vs step t dot-reads):
// writer passed barrier(t+1), which requires every thread to have finished
// its step-t dot (program order: dot(t) -> poll(t+1) -> barrier(t+1)).  Safe.
// ---------------------------------------------------------------------------
#define NWG 128
__global__ __launch_bounds__(256, 1) void lstm_scan(
    const float* __restrict__ Whh, const float* __restrict__ xg,
    const float* __restrict__ c0, unsigned long long* __restrict__ hpair,
    unsigned short* __restrict__ hs,
    float* __restrict__ outHT, float* __restrict__ outCT, int T)
{
    __shared__ float lh[2][1024];
    const int tid = threadIdx.x, blk = blockIdx.x;
    const int u = tid >> 5, s = tid & 31;
    const int j = blk * 8 + u;

    // stationary weights: w[g][k] = W_hh[g*1024+j][32*s + ((k+s)&31)]
    float w[4][32];
#pragma unroll
    for (int g = 0; g < 4; g++) {
        const float* wr = Whh + (size_t)(g * 1024 + j) * 1024 + s * 32;
#pragma unroll
        for (int k = 0; k < 32; k++) w[g][k] = wr[(k + s) & 31];
    }

    const bool owner = (s == 0);
    float cst = owner ? c0[j] : 0.f;

    for (int t = 0; t < T; t++) {
        // xg loads are independent of h: issue BEFORE the poll so the HBM
        // latency overlaps the wait for the previous step's producers.
        float xgi = 0.f, xgf = 0.f, xgg = 0.f, xgo = 0.f;
        if (owner) {
            const float* xp = xg + (size_t)t * 4096 + j;
            xgi = xp[0]; xgf = xp[1024]; xgg = xp[2048]; xgo = xp[3072];
        }

        // poll fused (tag,h) slots; tag match delivers the data directly.
        {
            const unsigned long long* hb = hpair + (size_t)(t & 1) * 1024;
            const unsigned int want = (unsigned int)t;
            bool g0 = false, g1 = false, g2 = false, g3 = false;
            do {
                if (!g0) {
                    unsigned long long v = __hip_atomic_load(
                        hb + tid, __ATOMIC_RELAXED, __HIP_MEMORY_SCOPE_AGENT);
                    if ((unsigned int)(v >> 32) == want) {
                        lh[t & 1][tid] = __builtin_bit_cast(float, (unsigned int)v);
                        g0 = true;
                    }
                }
                if (!g1) {
                    unsigned long long v = __hip_atomic_load(
                        hb + tid + 256, __ATOMIC_RELAXED, __HIP_MEMORY_SCOPE_AGENT);
                    if ((unsigned int)(v >> 32) == want) {
                        lh[t & 1][tid + 256] = __builtin_bit_cast(float, (unsigned int)v);
                        g1 = true;
                    }
                }
                if (!g2) {
                    unsigned long long v = __hip_atomic_load(
                        hb + tid + 512, __ATOMIC_RELAXED, __HIP_MEMORY_SCOPE_AGENT);
                    if ((unsigned int)(v >> 32) == want) {
                        lh[t & 1][tid + 512] = __builtin_bit_cast(float, (unsigned int)v);
                        g2 = true;
                    }
                }
                if (!g3) {
                    unsigned long long v = __hip_atomic_load(
                        hb + tid + 768, __ATOMIC_RELAXED, __HIP_MEMORY_SCOPE_AGENT);
                    if ((unsigned int)(v >> 32) == want) {
                        lh[t & 1][tid + 768] = __builtin_bit_cast(float, (unsigned int)v);
                        g3 = true;
                    }
                }
            } while (!(g0 && g1 && g2 && g3));
        }
        __syncthreads();   // LDS stage complete (the only barrier per step)

        float a0 = 0.f, a1 = 0.f, a2 = 0.f, a3 = 0.f;
        const float* lhp = &lh[t & 1][s * 32];
#pragma unroll
        for (int k = 0; k < 32; k++) {
            float hk = lhp[(k + s) & 31];
            a0 += w[0][k] * hk; a1 += w[1][k] * hk;
            a2 += w[2][k] * hk; a3 += w[3][k] * hk;
        }
#pragma unroll
        for (int d = 16; d; d >>= 1) {
            a0 += __shfl_down(a0, d, 32); a1 += __shfl_down(a1, d, 32);
            a2 += __shfl_down(a2, d, 32); a3 += __shfl_down(a3, d, 32);
        }

        if (owner) {
            float gi = xgi + a0, gf = xgf + a1, gg = xgg + a2, go = xgo + a3;
            float iv = 1.f / (1.f + __expf(-gi));
            float fv = 1.f / (1.f + __expf(-gf));
            float gv = tanhf(gg);
            float ov = 1.f / (1.f + __expf(-go));
            cst = fv * cst + iv * gv;
            float hv = ov * tanhf(cst);
            unsigned long long pv =
                ((unsigned long long)(unsigned int)(t + 1) << 32) |
                (unsigned long long)__builtin_bit_cast(unsigned int, hv);
            __hip_atomic_store(&hpair[(size_t)((t + 1) & 1) * 1024 + j], pv,
                               __ATOMIC_RELAXED, __HIP_MEMORY_SCOPE_AGENT);
            // hs only consumed by the next kernel: off the critical path.
            hs[(size_t)t * 1024 + j] = f2bf(hv);
            if (t == T - 1) { outHT[j] = hv; outCT[j] = cst; }
        }
        // no second barrier: LDS is parity double-buffered (see header proof)
    }
}

// ---------------------------------------------------------------------------
// In-place row log_softmax, fp32, V=32000. Two passes; pass 2 re-reads the
// L2-hot row. One WG (256 thr) per row, f32x4 vectorized (V/4 = 8000).
// ---------------------------------------------------------------------------
__global__ __launch_bounds__(256) void logsoftmax_rows(float* __restrict__ out, int V)
{
    __shared__ float redm[4], reds[4];
    const int tid = threadIdx.x;
    float* base = out + (size_t)blockIdx.x * V;
    const int n4 = V >> 2;

    float m = -3.0e38f, ssum = 0.f;
    for (int i = tid; i < n4; i += 256) {
        f32x4 v = ((const f32x4*)base)[i];
#pragma unroll
        for (int jj = 0; jj < 4; jj++) {
            float x = v[jj];
            if (x > m) { ssum = ssum * __expf(m - x) + 1.f; m = x; }
            else       { ssum += __expf(x - m); }
        }
    }
#pragma unroll
    for (int d = 32; d; d >>= 1) {
        float om = __shfl_down(m, d, 64);
        float os = __shfl_down(ssum, d, 64);
        float M = fmaxf(m, om);
        ssum = ssum * __expf(m - M) + os * __expf(om - M);
        m = M;
    }
    if ((tid & 63) == 0) { redm[tid >> 6] = m; reds[tid >> 6] = ssum; }
    __syncthreads();
    float M = fmaxf(fmaxf(redm[0], redm[1]), fmaxf(redm[2], redm[3]));
    float S = reds[0] * __expf(redm[0] - M) + reds[1] * __expf(redm[1] - M) +
              reds[2] * __expf(redm[2] - M) + reds[3] * __expf(redm[3] - M);
    float lse = M + logf(S);
    for (int i = tid; i < n4; i += 256) {
        f32x4 v = ((const f32x4*)base)[i];
        v.x -= lse; v.y -= lse; v.z -= lse; v.w -= lse;
        ((f32x4*)base)[i] = v;
    }
}

// ---------------------------------------------------------------------------
extern "C" void kernel_launch(void* const* d_in, const int* in_sizes, int n_in,
                              void* d_out, int out_size, void* d_ws, size_t ws_size,
                              hipStream_t stream)
{
    const int*   seq   = (const int*)d_in[0];
    const float* h0    = (const float*)d_in[1];
    const float* c0    = (const float*)d_in[2];
    const float* emb   = (const float*)d_in[3];
    const float* W_ih  = (const float*)d_in[4];
    const float* W_hh  = (const float*)d_in[5];
    const float* b_ih  = (const float*)d_in[6];
    const float* b_hh  = (const float*)d_in[7];
    const float* W_out = (const float*)d_in[8];
    const float* b_out = (const float*)d_in[9];

    const int T = 2048, H = 1024, V = 32000, G4 = 4096;

    // workspace layout (all regions fully written before read)
    char* ws = (char*)d_ws;
    float*          xg     = (float*)ws;                           // 33,554,432 B
    unsigned short* Woutb  = (unsigned short*)(ws + 33554432);     // 65,536,000 B
    unsigned short* Wihb   = (unsigned short*)(ws + 99090432);     //  8,388,608 B
    unsigned short* xbf    = (unsigned short*)(ws + 107479040);    //  4,194,304 B
    unsigned short* hs     = (unsigned short*)(ws + 111673344);    //  4,194,304 B
    unsigned long long* hpair = (unsigned long long*)(ws + 115867648); // 16,384 B

    float* outp  = (float*)d_out;
    float* outHT = outp + (size_t)T * V;
    float* outCT = outHT + H;

    init_h<<<4, 256, 0, stream>>>(h0, hpair);
    cast_f2b<<<(G4 * 1024 / 4 + 255) / 256, 256, 0, stream>>>(W_ih, Wihb, G4 * 1024 / 4);
    cast_f2b<<<(V * 1024 / 4 + 255) / 256, 256, 0, stream>>>(W_out, Woutb, V * 1024 / 4);
    gather_cast<<<T, 256, 0, stream>>>(seq, emb, xbf);

    // xg[T,4H] = xbf @ Wihb^T + (b_ih + b_hh), fp32
    gemm_bt<<<dim3(G4 / 64, T / 64), 256, 0, stream>>>(
        xbf, Wihb, b_ih, b_hh, xg, 1024, G4);

    // sequential scan -> hs[T,H] bf16, hT/cT fp32
    lstm_scan<<<NWG, 256, 0, stream>>>(W_hh, xg, c0, hpair, hs, outHT, outCT, T);

    // scores[T,V] = hs @ Woutb^T + b_out, fp32 directly into d_out
    gemm_bt<<<dim3(V / 64, T / 64), 256, 0, stream>>>(
        hs, Woutb, b_out, nullptr, outp, 1024, V);

    // in-place log_softmax per row
    logsoftmax_rows<<<T, 256, 0, stream>>>(outp, V);
}